// Round 1
// baseline (666.751 us; speedup 1.0000x reference)
//
#include <hip/hip_runtime.h>

#define HEADS 32
#define DK    64
#define NSEQ  2048
#define BATCH 2
#define DIN   512
#define INNER 2048  // HEADS*DK

typedef float f32x4 __attribute__((ext_vector_type(4)));
typedef short s16x8 __attribute__((ext_vector_type(8)));
typedef short s16x4 __attribute__((ext_vector_type(4)));

__device__ __forceinline__ short f2b(float f) {
  unsigned u = __float_as_uint(f);
  u += 0x7fffu + ((u >> 16) & 1u);   // round-to-nearest-even
  return (short)(u >> 16);
}

// ---------------- convert x: f32 -> bf16, vectorized ----------------
__global__ __launch_bounds__(256) void k_cvt(const float* __restrict__ in,
                                             short* __restrict__ out, int n4) {
  int i = blockIdx.x * 256 + threadIdx.x;
  if (i < n4) {
    float4 v = reinterpret_cast<const float4*>(in)[i];
    s16x4 o;
    o[0] = f2b(v.x); o[1] = f2b(v.y); o[2] = f2b(v.z); o[3] = f2b(v.w);
    reinterpret_cast<s16x4*>(out)[i] = o;
  }
}

// ------------- transpose W [R][C] f32 -> out [C][R] bf16 -------------
__global__ __launch_bounds__(256) void k_transpose(const float* __restrict__ in,
                                                   short* __restrict__ out,
                                                   int R, int C) {
  __shared__ float tile[64][65];
  const int tc = blockIdx.x * 64;   // input col tile
  const int tr = blockIdx.y * 64;   // input row tile
  const int tx = threadIdx.x & 63;
  const int ty = threadIdx.x >> 6;  // 0..3
#pragma unroll
  for (int rr = ty; rr < 64; rr += 4)
    tile[rr][tx] = in[(size_t)(tr + rr) * C + tc + tx];
  __syncthreads();
#pragma unroll
  for (int rr = ty; rr < 64; rr += 4)
    out[(size_t)(tc + rr) * R + tr + tx] = f2b(tile[tx][rr]);
}

// ---------------- GEMM: A[M][K] bf16 (k-fast) x BT[N][K] bf16 ----------------
// MODE 0: out bf16 laid out [B,H,N,DK]   (Q, K projections)
// MODE 2: out bf16 laid out [B,H,DK,N]   (V projection, pre-transposed)
// MODE 3: out f32 [M][N] with bias       (final projection)
template <int MODE>
__global__ __launch_bounds__(256) void k_gemm(const short* __restrict__ A,
                                              const short* __restrict__ BT,
                                              void* __restrict__ outp,
                                              const float* __restrict__ bias,
                                              int M, int N, int Kd) {
  const int bm = blockIdx.x * 128;
  const int bn = blockIdx.y * 64;
  const int wave = threadIdx.x >> 6, lane = threadIdx.x & 63;
  const int l16 = lane & 15, g = lane >> 4;
  const int m0 = bm + wave * 32;

  const f32x4 ZERO = {0.f, 0.f, 0.f, 0.f};
  f32x4 acc[2][4];
#pragma unroll
  for (int i = 0; i < 2; i++)
#pragma unroll
    for (int c = 0; c < 4; c++) acc[i][c] = ZERO;

  const short* arow0 = A + (size_t)(m0 + l16) * Kd + 8 * g;
  const short* arow1 = arow0 + (size_t)16 * Kd;

  for (int k0 = 0; k0 < Kd; k0 += 32) {
    s16x8 a0 = *reinterpret_cast<const s16x8*>(arow0 + k0);
    s16x8 a1 = *reinterpret_cast<const s16x8*>(arow1 + k0);
#pragma unroll
    for (int c = 0; c < 4; c++) {
      s16x8 bf = *reinterpret_cast<const s16x8*>(
          BT + (size_t)(bn + c * 16 + l16) * Kd + k0 + 8 * g);
      acc[0][c] = __builtin_amdgcn_mfma_f32_16x16x32_bf16(a0, bf, acc[0][c], 0, 0, 0);
      acc[1][c] = __builtin_amdgcn_mfma_f32_16x16x32_bf16(a1, bf, acc[1][c], 0, 0, 0);
    }
  }

#pragma unroll
  for (int i = 0; i < 2; i++)
#pragma unroll
    for (int c = 0; c < 4; c++)
#pragma unroll
      for (int r = 0; r < 4; r++) {
        int row = m0 + i * 16 + 4 * g + r;   // D: row=(lane>>4)*4+reg
        int col = bn + c * 16 + l16;         //    col=lane&15
        float v = acc[i][c][r];
        if (MODE == 3) {
          float* o = (float*)outp;
          o[(size_t)row * N + col] = v + bias[col];
        } else {
          short* o = (short*)outp;
          int b = row >> 11, n = row & 2047;
          int h = col >> 6, dk = col & 63;
          size_t idx;
          if (MODE == 2)
            idx = (((size_t)(b * HEADS + h)) * DK + dk) * NSEQ + n;
          else
            idx = (((size_t)(b * HEADS + h)) * NSEQ + n) * DK + dk;
          o[idx] = f2b(v);
        }
      }
}

// ---------------- flash attention ----------------
// Q,K: [B,H,N,64] bf16.  VT: [B,H,64,N] bf16.  att out: [B*N][H*64] bf16.
// grid = (N/64, H, B), block = 256 (4 waves x 16 q-rows each)
__global__ __launch_bounds__(256) void k_attn(const short* __restrict__ Q,
                                              const short* __restrict__ K,
                                              const short* __restrict__ VT,
                                              short* __restrict__ att) {
  const int qt = blockIdx.x, h = blockIdx.y, b = blockIdx.z;
  const int wave = threadIdx.x >> 6, lane = threadIdx.x & 63;
  const int l16 = lane & 15, g = lane >> 4;
  const int q0 = qt * 64 + wave * 16;
  const size_t hb = ((size_t)b * HEADS + h) * (size_t)NSEQ * DK;
  const short* Qh = Q + hb;
  const short* Kh = K + hb;
  const short* Vh = VT + hb;   // [64][NSEQ]

  // Q fragments (held whole kernel): A[q][dk], lane: Q[q0+l16][half*32+8g+j]
  s16x8 qf0 = *reinterpret_cast<const s16x8*>(Qh + (size_t)(q0 + l16) * DK + 8 * g);
  s16x8 qf1 = *reinterpret_cast<const s16x8*>(Qh + (size_t)(q0 + l16) * DK + 8 * g + 32);

  const f32x4 ZERO = {0.f, 0.f, 0.f, 0.f};
  float m[4], lsum[4];
  f32x4 o[4];
#pragma unroll
  for (int r = 0; r < 4; r++) { m[r] = -1e30f; lsum[r] = 0.f; }
#pragma unroll
  for (int c = 0; c < 4; c++) o[c] = ZERO;

  // wave-private P tile [16 q][32 k], stride 40 shorts (80B, 16B-aligned rows)
  __shared__ short plds[4][16][40];
  short(*pw)[40] = plds[wave];
  const float scale = 0.125f;  // 1/sqrt(64)

  for (int kc = 0; kc < NSEQ; kc += 32) {
    const short* kr0 = Kh + (size_t)(kc + l16) * DK + 8 * g;
    const short* kr1 = kr0 + 16 * DK;
    s16x8 kf00 = *reinterpret_cast<const s16x8*>(kr0);
    s16x8 kf01 = *reinterpret_cast<const s16x8*>(kr0 + 32);
    s16x8 kf10 = *reinterpret_cast<const s16x8*>(kr1);
    s16x8 kf11 = *reinterpret_cast<const s16x8*>(kr1 + 32);
    f32x4 s0 = ZERO, s1 = ZERO;
    s0 = __builtin_amdgcn_mfma_f32_16x16x32_bf16(qf0, kf00, s0, 0, 0, 0);
    s0 = __builtin_amdgcn_mfma_f32_16x16x32_bf16(qf1, kf01, s0, 0, 0, 0);
    s1 = __builtin_amdgcn_mfma_f32_16x16x32_bf16(qf0, kf10, s1, 0, 0, 0);
    s1 = __builtin_amdgcn_mfma_f32_16x16x32_bf16(qf1, kf11, s1, 0, 0, 0);

    __syncthreads();  // previous iteration's P reads done before overwrite
#pragma unroll
    for (int r = 0; r < 4; r++) {
      // S row = q0 + 4g + r, cols = l16 (tile0) and 16+l16 (tile1)
      float v = fmaxf(s0[r], s1[r]) * scale;
      v = fmaxf(v, __shfl_xor(v, 1));
      v = fmaxf(v, __shfl_xor(v, 2));
      v = fmaxf(v, __shfl_xor(v, 4));
      v = fmaxf(v, __shfl_xor(v, 8));
      float mnew = fmaxf(m[r], v);
      float alpha = __expf(m[r] - mnew);
      float p0 = __expf(s0[r] * scale - mnew);
      float p1 = __expf(s1[r] * scale - mnew);
      m[r] = mnew;
      float ps = p0 + p1;
      ps += __shfl_xor(ps, 1);
      ps += __shfl_xor(ps, 2);
      ps += __shfl_xor(ps, 4);
      ps += __shfl_xor(ps, 8);
      lsum[r] = lsum[r] * alpha + ps;
#pragma unroll
      for (int c = 0; c < 4; c++) o[c][r] *= alpha;
      pw[4 * g + r][l16]      = f2b(p0);
      pw[4 * g + r][16 + l16] = f2b(p1);
    }
    __syncthreads();  // P writes visible before fragment read

    // P A-frag: P[l16][8g+j] ; V B-frag: VT[c*16+l16][kc+8g+j] (16B contiguous)
    s16x8 pf = *reinterpret_cast<const s16x8*>(&pw[l16][8 * g]);
#pragma unroll
    for (int c = 0; c < 4; c++) {
      s16x8 vf = *reinterpret_cast<const s16x8*>(
          Vh + (size_t)(c * 16 + l16) * NSEQ + kc + 8 * g);
      o[c] = __builtin_amdgcn_mfma_f32_16x16x32_bf16(pf, vf, o[c], 0, 0, 0);
    }
  }

#pragma unroll
  for (int r = 0; r < 4; r++) {
    float inv = 1.f / lsum[r];
    size_t row = ((size_t)b * NSEQ + q0 + 4 * g + r) * INNER + (size_t)h * DK;
#pragma unroll
    for (int c = 0; c < 4; c++)
      att[row + c * 16 + l16] = f2b(o[c][r] * inv);
  }
}

extern "C" void kernel_launch(void* const* d_in, const int* in_sizes, int n_in,
                              void* d_out, int out_size, void* d_ws, size_t ws_size,
                              hipStream_t stream) {
  const float* x  = (const float*)d_in[0];
  const float* Wq = (const float*)d_in[1];
  const float* Wk = (const float*)d_in[2];
  const float* Wv = (const float*)d_in[3];
  const float* Wz = (const float*)d_in[4];
  const float* bz = (const float*)d_in[5];

  char* ws = (char*)d_ws;
  const size_t MB = (size_t)1 << 20;
  short* xb  = (short*)(ws);              // [4096][512]      4 MB
  short* wqt = (short*)(ws + 4 * MB);     // [2048][512]      2 MB
  short* wkt = (short*)(ws + 6 * MB);     // [2048][512]      2 MB
  short* wvt = (short*)(ws + 8 * MB);     // [2048][512]      2 MB
  short* wzt = (short*)(ws + 10 * MB);    // [512][2048]      2 MB
  short* Qb  = (short*)(ws + 12 * MB);    // [2,32,2048,64]  16 MB
  short* Kb  = (short*)(ws + 28 * MB);    // [2,32,2048,64]  16 MB
  short* Vt  = (short*)(ws + 44 * MB);    // [2,32,64,2048]  16 MB
  short* att = (short*)(ws + 60 * MB);    // [4096][2048]    16 MB  (total 76 MB)

  k_cvt<<<2048, 256, 0, stream>>>(x, xb, (BATCH * NSEQ * DIN) / 4);
  k_transpose<<<dim3(32, 8), 256, 0, stream>>>(Wq, wqt, DIN, INNER);
  k_transpose<<<dim3(32, 8), 256, 0, stream>>>(Wk, wkt, DIN, INNER);
  k_transpose<<<dim3(32, 8), 256, 0, stream>>>(Wv, wvt, DIN, INNER);
  k_transpose<<<dim3(8, 32), 256, 0, stream>>>(Wz, wzt, INNER, DIN);

  dim3 gQKV(32, 32);  // M/128, N/64
  k_gemm<0><<<gQKV, 256, 0, stream>>>(xb, wqt, Qb, nullptr, 4096, INNER, DIN);
  k_gemm<0><<<gQKV, 256, 0, stream>>>(xb, wkt, Kb, nullptr, 4096, INNER, DIN);
  k_gemm<2><<<gQKV, 256, 0, stream>>>(xb, wvt, Vt, nullptr, 4096, INNER, DIN);

  k_attn<<<dim3(NSEQ / 64, HEADS, BATCH), 256, 0, stream>>>(Qb, Kb, Vt, att);

  k_gemm<3><<<dim3(32, 8), 256, 0, stream>>>(att, wzt, d_out, bz, 4096, DIN, INNER);
}

// Round 2
// 497.639 us; speedup vs baseline: 1.3398x; 1.3398x over previous
//
#include <hip/hip_runtime.h>

#define HEADS 32
#define DK    64
#define NSEQ  2048
#define BATCH 2
#define DIN   512
#define INNER 2048  // HEADS*DK

typedef float f32x4 __attribute__((ext_vector_type(4)));
typedef float f32x16 __attribute__((ext_vector_type(16)));
typedef short s16x8 __attribute__((ext_vector_type(8)));
typedef short s16x4 __attribute__((ext_vector_type(4)));
typedef unsigned u32x4 __attribute__((ext_vector_type(4)));

__device__ __forceinline__ short f2b(float f) {
  unsigned u = __float_as_uint(f);
  u += 0x7fffu + ((u >> 16) & 1u);   // round-to-nearest-even
  return (short)(u >> 16);
}

__device__ __forceinline__ unsigned cvt_pk_bf16(float lo, float hi) {
  unsigned r;
  asm("v_cvt_pk_bf16_f32 %0, %1, %2" : "=v"(r) : "v"(lo), "v"(hi));
  return r;
}

// ---------------- convert x: f32 -> bf16, vectorized ----------------
__global__ __launch_bounds__(256) void k_cvt(const float* __restrict__ in,
                                             short* __restrict__ out, int n4) {
  int i = blockIdx.x * 256 + threadIdx.x;
  if (i < n4) {
    float4 v = reinterpret_cast<const float4*>(in)[i];
    s16x4 o;
    o[0] = f2b(v.x); o[1] = f2b(v.y); o[2] = f2b(v.z); o[3] = f2b(v.w);
    reinterpret_cast<s16x4*>(out)[i] = o;
  }
}

// ------------- transpose W [R][C] f32 -> out [C][R] bf16 -------------
__global__ __launch_bounds__(256) void k_transpose(const float* __restrict__ in,
                                                   short* __restrict__ out,
                                                   int R, int C) {
  __shared__ float tile[64][65];
  const int tc = blockIdx.x * 64;
  const int tr = blockIdx.y * 64;
  const int tx = threadIdx.x & 63;
  const int ty = threadIdx.x >> 6;
#pragma unroll
  for (int rr = ty; rr < 64; rr += 4)
    tile[rr][tx] = in[(size_t)(tr + rr) * C + tc + tx];
  __syncthreads();
#pragma unroll
  for (int rr = ty; rr < 64; rr += 4)
    out[(size_t)(tc + rr) * R + tr + tx] = f2b(tile[tx][rr]);
}

// ---------------- GEMM: A[M][K] bf16 (k-fast) x BT[N][K] bf16 ----------------
// MODE 0: out bf16 [B,H,N,DK]            (K projection)
// MODE 1: out bf16 [B,H,N,DK], *0.125    (Q projection, softmax scale folded)
// MODE 2: out bf16 [B,H,DK,N]            (V projection, pre-transposed)
// MODE 3: out f32 [M][N] + bias          (final projection)
template <int MODE>
__global__ __launch_bounds__(256) void k_gemm(const short* __restrict__ A,
                                              const short* __restrict__ BT,
                                              void* __restrict__ outp,
                                              const float* __restrict__ bias,
                                              int M, int N, int Kd) {
  const int bm = blockIdx.x * 128;
  const int bn = blockIdx.y * 64;
  const int wave = threadIdx.x >> 6, lane = threadIdx.x & 63;
  const int l16 = lane & 15, g = lane >> 4;
  const int m0 = bm + wave * 32;

  const f32x4 ZERO = {0.f, 0.f, 0.f, 0.f};
  f32x4 acc[2][4];
#pragma unroll
  for (int i = 0; i < 2; i++)
#pragma unroll
    for (int c = 0; c < 4; c++) acc[i][c] = ZERO;

  const short* arow0 = A + (size_t)(m0 + l16) * Kd + 8 * g;
  const short* arow1 = arow0 + (size_t)16 * Kd;

  for (int k0 = 0; k0 < Kd; k0 += 32) {
    s16x8 a0 = *reinterpret_cast<const s16x8*>(arow0 + k0);
    s16x8 a1 = *reinterpret_cast<const s16x8*>(arow1 + k0);
#pragma unroll
    for (int c = 0; c < 4; c++) {
      s16x8 bf = *reinterpret_cast<const s16x8*>(
          BT + (size_t)(bn + c * 16 + l16) * Kd + k0 + 8 * g);
      acc[0][c] = __builtin_amdgcn_mfma_f32_16x16x32_bf16(a0, bf, acc[0][c], 0, 0, 0);
      acc[1][c] = __builtin_amdgcn_mfma_f32_16x16x32_bf16(a1, bf, acc[1][c], 0, 0, 0);
    }
  }

#pragma unroll
  for (int i = 0; i < 2; i++)
#pragma unroll
    for (int c = 0; c < 4; c++)
#pragma unroll
      for (int r = 0; r < 4; r++) {
        int row = m0 + i * 16 + 4 * g + r;
        int col = bn + c * 16 + l16;
        float v = acc[i][c][r];
        if (MODE == 3) {
          float* o = (float*)outp;
          o[(size_t)row * N + col] = v + bias[col];
        } else {
          if (MODE == 1) v *= 0.125f;  // 1/sqrt(64), exact in bf16
          short* o = (short*)outp;
          int b = row >> 11, n = row & 2047;
          int h = col >> 6, dk = col & 63;
          size_t idx;
          if (MODE == 2)
            idx = (((size_t)(b * HEADS + h)) * DK + dk) * NSEQ + n;
          else
            idx = (((size_t)(b * HEADS + h)) * NSEQ + n) * DK + dk;
          o[idx] = f2b(v);
        }
      }
}

// ---------------- flash attention, swapped-QK^T in-register softmax ----------
// Q (pre-scaled), K: [B,H,N,64] bf16.  VT: [B,H,64,N] bf16.
// att out: [B*N][H*64] bf16.
// grid = (N/128, H, B), block = 256 = 4 independent waves, 32 q-rows each.
// S^T = mfma_32x32x16(K, Q): lane holds S[q = q0+(lane&31)][kv], 16 regs,
//   kv = (r&3) + 8*(r>>2) + 4*(lane>>5)  -> row softmax is lane-local.
__global__ __launch_bounds__(256) void k_attn(const short* __restrict__ Q,
                                              const short* __restrict__ K,
                                              const short* __restrict__ VT,
                                              short* __restrict__ att) {
  const int wave = threadIdx.x >> 6, lane = threadIdx.x & 63;
  const int l32 = lane & 31, hi = lane >> 5;
  const int h = blockIdx.y, b = blockIdx.z;
  const int q0 = blockIdx.x * 128 + wave * 32;
  const size_t hb = ((size_t)b * HEADS + h) * (size_t)NSEQ * DK;
  const short* Qh = Q + hb;
  const short* Kh = K + hb;
  const short* Vh = VT + hb;  // [64][NSEQ]

  // Q B-frags (held whole kernel): lane supplies Q[q0+l32][c*16 + 8*hi + j]
  s16x8 qf[4];
  {
    const short* qrow = Qh + (size_t)(q0 + l32) * DK + 8 * hi;
#pragma unroll
    for (int c = 0; c < 4; c++) qf[c] = *reinterpret_cast<const s16x8*>(qrow + 16 * c);
  }

  f32x16 ot[2] = {};              // O^T accum: d-tiles 0/1, col=q, row=d
  float m = -1e30f, lsum = 0.f;

  // prefetch K tile 0: lane supplies K[kv0+l32][c*16 + 8*hi + j]
  s16x8 kf[4];
  {
    const short* krow = Kh + (size_t)l32 * DK + 8 * hi;
#pragma unroll
    for (int c = 0; c < 4; c++) kf[c] = *reinterpret_cast<const s16x8*>(krow + 16 * c);
  }

  for (int kc = 0; kc < NSEQ; kc += 32) {
    // V A-frags for this tile (independent of softmax -> issues early):
    // lane supplies VT[dt*32 + l32][kc + ks*16 + 8*hi + j]
    s16x8 vf[2][2];
#pragma unroll
    for (int dt = 0; dt < 2; dt++)
#pragma unroll
      for (int ks = 0; ks < 2; ks++)
        vf[dt][ks] = *reinterpret_cast<const s16x8*>(
            Vh + (size_t)(dt * 32 + l32) * NSEQ + kc + ks * 16 + 8 * hi);

    // prefetch next K tile
    s16x8 kn[4];
    if (kc + 32 < NSEQ) {
      const short* krow = Kh + (size_t)(kc + 32 + l32) * DK + 8 * hi;
#pragma unroll
      for (int c = 0; c < 4; c++) kn[c] = *reinterpret_cast<const s16x8*>(krow + 16 * c);
    } else {
#pragma unroll
      for (int c = 0; c < 4; c++) kn[c] = kf[c];
    }

    // S^T = K . Q^T  (scale already folded into Q)
    f32x16 st = {};
#pragma unroll
    for (int c = 0; c < 4; c++)
      st = __builtin_amdgcn_mfma_f32_32x32x16_bf16(kf[c], qf[c], st, 0, 0, 0);

    // ---- online softmax, lane-local ----
    float mx;
    {
      float t0 = fmaxf(fmaxf(st[0], st[1]), fmaxf(st[2], st[3]));
      float t1 = fmaxf(fmaxf(st[4], st[5]), fmaxf(st[6], st[7]));
      float t2 = fmaxf(fmaxf(st[8], st[9]), fmaxf(st[10], st[11]));
      float t3 = fmaxf(fmaxf(st[12], st[13]), fmaxf(st[14], st[15]));
      mx = fmaxf(fmaxf(t0, t1), fmaxf(t2, t3));
    }
    mx = fmaxf(mx, __shfl_xor(mx, 32));

    if (!__all(mx <= m + 8.f)) {     // defer-max (T13, THR=8)
      float mnew = fmaxf(m, mx);
      float alpha = __expf(m - mnew);
      lsum *= alpha;
#pragma unroll
      for (int r = 0; r < 16; r++) { ot[0][r] *= alpha; ot[1][r] *= alpha; }
      m = mnew;
    }

    float p[16];
#pragma unroll
    for (int r = 0; r < 16; r++) p[r] = __expf(st[r] - m);
    {
      float s0 = (p[0] + p[1]) + (p[2] + p[3]);
      float s1 = (p[4] + p[5]) + (p[6] + p[7]);
      float s2 = (p[8] + p[9]) + (p[10] + p[11]);
      float s3 = (p[12] + p[13]) + (p[14] + p[15]);
      float ps = (s0 + s1) + (s2 + s3);
      ps += __shfl_xor(ps, 32);
      lsum += ps;
    }

    // ---- P^T B-frag build: cvt_pk pairs + half-swap (T12 pattern) ----
    unsigned a0 = cvt_pk_bf16(p[0], p[1]),   a1 = cvt_pk_bf16(p[2], p[3]);
    unsigned a2 = cvt_pk_bf16(p[4], p[5]),   a3 = cvt_pk_bf16(p[6], p[7]);
    unsigned a4 = cvt_pk_bf16(p[8], p[9]),   a5 = cvt_pk_bf16(p[10], p[11]);
    unsigned a6 = cvt_pk_bf16(p[12], p[13]), a7 = cvt_pk_bf16(p[14], p[15]);
    unsigned x0 = __shfl_xor(a0, 32), x1 = __shfl_xor(a1, 32);
    unsigned x2 = __shfl_xor(a2, 32), x3 = __shfl_xor(a3, 32);
    unsigned x4 = __shfl_xor(a4, 32), x5 = __shfl_xor(a5, 32);
    unsigned x6 = __shfl_xor(a6, 32), x7 = __shfl_xor(a7, 32);

    // ksub 0 covers kv[0..15]: B-frag lane needs kv = 8*hi + j
    u32x4 pw0, pw1;
    pw0[0] = hi ? x2 : a0;  pw0[1] = hi ? x3 : a1;
    pw0[2] = hi ? a2 : x0;  pw0[3] = hi ? a3 : x1;
    pw1[0] = hi ? x6 : a4;  pw1[1] = hi ? x7 : a5;
    pw1[2] = hi ? a6 : x4;  pw1[3] = hi ? a7 : x5;
    s16x8 pf0 = __builtin_bit_cast(s16x8, pw0);
    s16x8 pf1 = __builtin_bit_cast(s16x8, pw1);

    // O^T += V^T . P^T
    ot[0] = __builtin_amdgcn_mfma_f32_32x32x16_bf16(vf[0][0], pf0, ot[0], 0, 0, 0);
    ot[1] = __builtin_amdgcn_mfma_f32_32x32x16_bf16(vf[1][0], pf0, ot[1], 0, 0, 0);
    ot[0] = __builtin_amdgcn_mfma_f32_32x32x16_bf16(vf[0][1], pf1, ot[0], 0, 0, 0);
    ot[1] = __builtin_amdgcn_mfma_f32_32x32x16_bf16(vf[1][1], pf1, ot[1], 0, 0, 0);

#pragma unroll
    for (int c = 0; c < 4; c++) kf[c] = kn[c];
  }

  // epilogue: normalize + write att[B*N][H*64]
  float inv = 1.f / lsum;
  size_t arow = ((size_t)b * NSEQ + q0 + l32) * INNER + (size_t)h * DK;
#pragma unroll
  for (int dt = 0; dt < 2; dt++)
#pragma unroll
    for (int gq = 0; gq < 4; gq++) {
      s16x4 w;
#pragma unroll
      for (int j = 0; j < 4; j++) w[j] = f2b(ot[dt][4 * gq + j] * inv);
      *reinterpret_cast<s16x4*>(att + arow + dt * 32 + 8 * gq + 4 * hi) = w;
    }
}

extern "C" void kernel_launch(void* const* d_in, const int* in_sizes, int n_in,
                              void* d_out, int out_size, void* d_ws, size_t ws_size,
                              hipStream_t stream) {
  const float* x  = (const float*)d_in[0];
  const float* Wq = (const float*)d_in[1];
  const float* Wk = (const float*)d_in[2];
  const float* Wv = (const float*)d_in[3];
  const float* Wz = (const float*)d_in[4];
  const float* bz = (const float*)d_in[5];

  char* ws = (char*)d_ws;
  const size_t MB = (size_t)1 << 20;
  short* xb  = (short*)(ws);              // [4096][512]      4 MB
  short* wqt = (short*)(ws + 4 * MB);     // [2048][512]      2 MB
  short* wkt = (short*)(ws + 6 * MB);     // [2048][512]      2 MB
  short* wvt = (short*)(ws + 8 * MB);     // [2048][512]      2 MB
  short* wzt = (short*)(ws + 10 * MB);    // [512][2048]      2 MB
  short* Qb  = (short*)(ws + 12 * MB);    // [2,32,2048,64]  16 MB
  short* Kb  = (short*)(ws + 28 * MB);    // [2,32,2048,64]  16 MB
  short* Vt  = (short*)(ws + 44 * MB);    // [2,32,64,2048]  16 MB
  short* att = (short*)(ws + 60 * MB);    // [4096][2048]    16 MB

  k_cvt<<<2048, 256, 0, stream>>>(x, xb, (BATCH * NSEQ * DIN) / 4);
  k_transpose<<<dim3(32, 8), 256, 0, stream>>>(Wq, wqt, DIN, INNER);
  k_transpose<<<dim3(32, 8), 256, 0, stream>>>(Wk, wkt, DIN, INNER);
  k_transpose<<<dim3(32, 8), 256, 0, stream>>>(Wv, wvt, DIN, INNER);
  k_transpose<<<dim3(8, 32), 256, 0, stream>>>(Wz, wzt, INNER, DIN);

  dim3 gQKV(32, 32);  // M/128, N/64
  k_gemm<1><<<gQKV, 256, 0, stream>>>(xb, wqt, Qb, nullptr, 4096, INNER, DIN);
  k_gemm<0><<<gQKV, 256, 0, stream>>>(xb, wkt, Kb, nullptr, 4096, INNER, DIN);
  k_gemm<2><<<gQKV, 256, 0, stream>>>(xb, wvt, Vt, nullptr, 4096, INNER, DIN);

  k_attn<<<dim3(NSEQ / 128, HEADS, BATCH), 256, 0, stream>>>(Qb, Kb, Vt, att);

  k_gemm<3><<<dim3(32, 8), 256, 0, stream>>>(att, wzt, d_out, bz, 4096, DIN, INNER);
}

// Round 3
// 338.458 us; speedup vs baseline: 1.9700x; 1.4703x over previous
//
#include <hip/hip_runtime.h>

#define HEADS 32
#define DK    64
#define NSEQ  2048
#define BATCH 2
#define DIN   512
#define INNER 2048  // HEADS*DK

typedef float f32x4 __attribute__((ext_vector_type(4)));
typedef float f32x16 __attribute__((ext_vector_type(16)));
typedef short s16x8 __attribute__((ext_vector_type(8)));
typedef short s16x4 __attribute__((ext_vector_type(4)));
typedef unsigned u32x4 __attribute__((ext_vector_type(4)));

__device__ __forceinline__ short f2b(float f) {
  unsigned u = __float_as_uint(f);
  u += 0x7fffu + ((u >> 16) & 1u);   // round-to-nearest-even
  return (short)(u >> 16);
}

__device__ __forceinline__ unsigned cvt_pk_bf16(float lo, float hi) {
  unsigned r;
  asm("v_cvt_pk_bf16_f32 %0, %1, %2" : "=v"(r) : "v"(lo), "v"(hi));
  return r;
}

// ---------------- convert x: f32 -> bf16, vectorized ----------------
__global__ __launch_bounds__(256) void k_cvt(const float* __restrict__ in,
                                             short* __restrict__ out, int n4) {
  int i = blockIdx.x * 256 + threadIdx.x;
  if (i < n4) {
    float4 v = reinterpret_cast<const float4*>(in)[i];
    s16x4 o;
    o[0] = f2b(v.x); o[1] = f2b(v.y); o[2] = f2b(v.z); o[3] = f2b(v.w);
    reinterpret_cast<s16x4*>(out)[i] = o;
  }
}

// ------------- transpose W [R][C] f32 -> out [C][R] bf16 -------------
__global__ __launch_bounds__(256) void k_transpose(const float* __restrict__ in,
                                                   short* __restrict__ out,
                                                   int R, int C) {
  __shared__ float tile[64][65];
  const int tc = blockIdx.x * 64;
  const int tr = blockIdx.y * 64;
  const int tx = threadIdx.x & 63;
  const int ty = threadIdx.x >> 6;
#pragma unroll
  for (int rr = ty; rr < 64; rr += 4)
    tile[rr][tx] = in[(size_t)(tr + rr) * C + tc + tx];
  __syncthreads();
#pragma unroll
  for (int rr = ty; rr < 64; rr += 4)
    out[(size_t)(tc + rr) * R + tr + tx] = f2b(tile[tx][rr]);
}

// Fragment-linear layouts per (b,h), elements (n in [0,2048), dk in [0,64)):
//  Q/K (B-operand of 32x32x16, 32-row kv/q tiles):
//    lin = ((n>>5)*4 + (dk>>4))*512 + ((dk>>3)&1)*256 + (n&31)*8 + (dk&7)
//    -> lane (l32=n&31, hi=(dk>>3)&1) holds 16B chunk; load = base + lane*8 shorts
//  V (A-operand of PV, transposed consumption):
//    lin = ((n>>5)*2 + ((n>>4)&1))*1024 + (dk>>5)*512 + ((n>>3)&1)*256 + (dk&31)*8 + (n&7)

// ---------------- GEMM: A[M][K] bf16 (k-fast) x BT[N][K] bf16 ----------------
// MODE 0: out bf16 frag-linear Q/K layout       (K projection)
// MODE 1: MODE 0 * 0.125                        (Q projection, scale folded)
// MODE 2: out bf16 frag-linear V layout         (V projection)
// MODE 3: out f32 [M][N] + bias                 (final projection)
template <int MODE>
__global__ __launch_bounds__(256) void k_gemm(const short* __restrict__ A,
                                              const short* __restrict__ BT,
                                              void* __restrict__ outp,
                                              const float* __restrict__ bias,
                                              int M, int N, int Kd) {
  const int bm = blockIdx.x * 128;
  const int bn = blockIdx.y * 64;
  const int wave = threadIdx.x >> 6, lane = threadIdx.x & 63;
  const int l16 = lane & 15, g = lane >> 4;
  const int m0 = bm + wave * 32;

  const f32x4 ZERO = {0.f, 0.f, 0.f, 0.f};
  f32x4 acc[2][4];
#pragma unroll
  for (int i = 0; i < 2; i++)
#pragma unroll
    for (int c = 0; c < 4; c++) acc[i][c] = ZERO;

  const short* arow0 = A + (size_t)(m0 + l16) * Kd + 8 * g;
  const short* arow1 = arow0 + (size_t)16 * Kd;

  for (int k0 = 0; k0 < Kd; k0 += 32) {
    s16x8 a0 = *reinterpret_cast<const s16x8*>(arow0 + k0);
    s16x8 a1 = *reinterpret_cast<const s16x8*>(arow1 + k0);
#pragma unroll
    for (int c = 0; c < 4; c++) {
      s16x8 bf = *reinterpret_cast<const s16x8*>(
          BT + (size_t)(bn + c * 16 + l16) * Kd + k0 + 8 * g);
      acc[0][c] = __builtin_amdgcn_mfma_f32_16x16x32_bf16(a0, bf, acc[0][c], 0, 0, 0);
      acc[1][c] = __builtin_amdgcn_mfma_f32_16x16x32_bf16(a1, bf, acc[1][c], 0, 0, 0);
    }
  }

#pragma unroll
  for (int i = 0; i < 2; i++)
#pragma unroll
    for (int c = 0; c < 4; c++)
#pragma unroll
      for (int r = 0; r < 4; r++) {
        int row = m0 + i * 16 + 4 * g + r;
        int col = bn + c * 16 + l16;
        float v = acc[i][c][r];
        if (MODE == 3) {
          float* o = (float*)outp;
          o[(size_t)row * N + col] = v + bias[col];
        } else {
          if (MODE == 1) v *= 0.125f;  // 1/sqrt(64), exact in bf16
          short* o = (short*)outp;
          int b = row >> 11, n = row & 2047;
          int h = col >> 6, dk = col & 63;
          size_t base = (size_t)(b * HEADS + h) * (NSEQ * DK);
          size_t idx;
          if (MODE == 2)
            idx = base + (size_t)((n >> 5) * 2 + ((n >> 4) & 1)) * 1024 +
                  (dk >> 5) * 512 + ((n >> 3) & 1) * 256 + (dk & 31) * 8 + (n & 7);
          else
            idx = base + (size_t)((n >> 5) * 4 + (dk >> 4)) * 512 +
                  ((dk >> 3) & 1) * 256 + (n & 31) * 8 + (dk & 7);
          o[idx] = f2b(v);
        }
      }
}

// ---------------- flash attention, swapped-QK^T in-register softmax ----------
// Q (pre-scaled), K, V in fragment-linear layouts (see above).
// att out: [B*N][H*64] bf16.
// grid = (N/64, H, B), block = 128 = 2 independent waves, 32 q-rows each.
__global__ __launch_bounds__(128) void k_attn(const short* __restrict__ Q,
                                              const short* __restrict__ K,
                                              const short* __restrict__ VT,
                                              short* __restrict__ att) {
  const int wave = threadIdx.x >> 6, lane = threadIdx.x & 63;
  const int l32 = lane & 31, hi = lane >> 5;
  const int h = blockIdx.y, b = blockIdx.z;
  const int q0 = blockIdx.x * 64 + wave * 32;
  const size_t hb = ((size_t)b * HEADS + h) * (size_t)NSEQ * DK;
  const short* Qh = Q + hb;
  const short* Kh = K + hb;
  const short* Vh = VT + hb;

  // Q B-frags: fully coalesced, base + lane*16B
  s16x8 qf[4];
  {
    const short* qbase = Qh + (size_t)(q0 >> 5) * 2048 + lane * 8;
#pragma unroll
    for (int c = 0; c < 4; c++) qf[c] = *reinterpret_cast<const s16x8*>(qbase + c * 512);
  }

  f32x16 ot[2] = {};              // O^T accum: d-tiles 0/1, col=q, row=d
  float m = -1e30f, lsum = 0.f;

  // prefetch K tile 0
  s16x8 kf[4];
  {
    const short* kbase = Kh + lane * 8;
#pragma unroll
    for (int c = 0; c < 4; c++) kf[c] = *reinterpret_cast<const s16x8*>(kbase + c * 512);
  }

  for (int tk = 0; tk < NSEQ / 32; ++tk) {
    // V A-frags for this tile (independent of softmax -> issue early)
    s16x8 vf[2][2];
    {
      const short* vbase = Vh + (size_t)tk * 2048 + lane * 8;
#pragma unroll
      for (int ks = 0; ks < 2; ks++)
#pragma unroll
        for (int dt = 0; dt < 2; dt++)
          vf[dt][ks] = *reinterpret_cast<const s16x8*>(vbase + (ks * 2 + dt) * 512);
    }

    // prefetch next K tile
    s16x8 kn[4];
    if (tk + 1 < NSEQ / 32) {
      const short* kbase = Kh + (size_t)(tk + 1) * 2048 + lane * 8;
#pragma unroll
      for (int c = 0; c < 4; c++) kn[c] = *reinterpret_cast<const s16x8*>(kbase + c * 512);
    } else {
#pragma unroll
      for (int c = 0; c < 4; c++) kn[c] = kf[c];
    }

    // S^T = K . Q^T  (scale already folded into Q)
    f32x16 st = {};
#pragma unroll
    for (int c = 0; c < 4; c++)
      st = __builtin_amdgcn_mfma_f32_32x32x16_bf16(kf[c], qf[c], st, 0, 0, 0);

    // ---- online softmax, lane-local ----
    float mx;
    {
      float t0 = fmaxf(fmaxf(st[0], st[1]), fmaxf(st[2], st[3]));
      float t1 = fmaxf(fmaxf(st[4], st[5]), fmaxf(st[6], st[7]));
      float t2 = fmaxf(fmaxf(st[8], st[9]), fmaxf(st[10], st[11]));
      float t3 = fmaxf(fmaxf(st[12], st[13]), fmaxf(st[14], st[15]));
      mx = fmaxf(fmaxf(t0, t1), fmaxf(t2, t3));
    }
    mx = fmaxf(mx, __shfl_xor(mx, 32));

    if (!__all(mx <= m + 8.f)) {     // defer-max (T13, THR=8)
      float mnew = fmaxf(m, mx);
      float alpha = __expf(m - mnew);
      lsum *= alpha;
#pragma unroll
      for (int r = 0; r < 16; r++) { ot[0][r] *= alpha; ot[1][r] *= alpha; }
      m = mnew;
    }

    float p[16];
#pragma unroll
    for (int r = 0; r < 16; r++) p[r] = __expf(st[r] - m);
    {
      float s0 = (p[0] + p[1]) + (p[2] + p[3]);
      float s1 = (p[4] + p[5]) + (p[6] + p[7]);
      float s2 = (p[8] + p[9]) + (p[10] + p[11]);
      float s3 = (p[12] + p[13]) + (p[14] + p[15]);
      float ps = (s0 + s1) + (s2 + s3);
      ps += __shfl_xor(ps, 32);
      lsum += ps;
    }

    // ---- P^T B-frag build: cvt_pk pairs + half-swap (T12 pattern) ----
    unsigned a0 = cvt_pk_bf16(p[0], p[1]),   a1 = cvt_pk_bf16(p[2], p[3]);
    unsigned a2 = cvt_pk_bf16(p[4], p[5]),   a3 = cvt_pk_bf16(p[6], p[7]);
    unsigned a4 = cvt_pk_bf16(p[8], p[9]),   a5 = cvt_pk_bf16(p[10], p[11]);
    unsigned a6 = cvt_pk_bf16(p[12], p[13]), a7 = cvt_pk_bf16(p[14], p[15]);
    unsigned x0 = __shfl_xor(a0, 32), x1 = __shfl_xor(a1, 32);
    unsigned x2 = __shfl_xor(a2, 32), x3 = __shfl_xor(a3, 32);
    unsigned x4 = __shfl_xor(a4, 32), x5 = __shfl_xor(a5, 32);
    unsigned x6 = __shfl_xor(a6, 32), x7 = __shfl_xor(a7, 32);

    u32x4 pw0, pw1;
    pw0[0] = hi ? x2 : a0;  pw0[1] = hi ? x3 : a1;
    pw0[2] = hi ? a2 : x0;  pw0[3] = hi ? a3 : x1;
    pw1[0] = hi ? x6 : a4;  pw1[1] = hi ? x7 : a5;
    pw1[2] = hi ? a6 : x4;  pw1[3] = hi ? a7 : x5;
    s16x8 pf0 = __builtin_bit_cast(s16x8, pw0);
    s16x8 pf1 = __builtin_bit_cast(s16x8, pw1);

    // O^T += V^T . P^T
    ot[0] = __builtin_amdgcn_mfma_f32_32x32x16_bf16(vf[0][0], pf0, ot[0], 0, 0, 0);
    ot[1] = __builtin_amdgcn_mfma_f32_32x32x16_bf16(vf[1][0], pf0, ot[1], 0, 0, 0);
    ot[0] = __builtin_amdgcn_mfma_f32_32x32x16_bf16(vf[0][1], pf1, ot[0], 0, 0, 0);
    ot[1] = __builtin_amdgcn_mfma_f32_32x32x16_bf16(vf[1][1], pf1, ot[1], 0, 0, 0);

#pragma unroll
    for (int c = 0; c < 4; c++) kf[c] = kn[c];
  }

  // epilogue: normalize + write att[B*N][H*64]
  float inv = 1.f / lsum;
  size_t arow = ((size_t)b * NSEQ + q0 + l32) * INNER + (size_t)h * DK;
#pragma unroll
  for (int dt = 0; dt < 2; dt++)
#pragma unroll
    for (int gq = 0; gq < 4; gq++) {
      s16x4 w;
#pragma unroll
      for (int j = 0; j < 4; j++) w[j] = f2b(ot[dt][4 * gq + j] * inv);
      *reinterpret_cast<s16x4*>(att + arow + dt * 32 + 8 * gq + 4 * hi) = w;
    }
}

extern "C" void kernel_launch(void* const* d_in, const int* in_sizes, int n_in,
                              void* d_out, int out_size, void* d_ws, size_t ws_size,
                              hipStream_t stream) {
  const float* x  = (const float*)d_in[0];
  const float* Wq = (const float*)d_in[1];
  const float* Wk = (const float*)d_in[2];
  const float* Wv = (const float*)d_in[3];
  const float* Wz = (const float*)d_in[4];
  const float* bz = (const float*)d_in[5];

  char* ws = (char*)d_ws;
  const size_t MB = (size_t)1 << 20;
  short* xb  = (short*)(ws);              // [4096][512]      4 MB
  short* wqt = (short*)(ws + 4 * MB);     // [2048][512]      2 MB
  short* wkt = (short*)(ws + 6 * MB);     // [2048][512]      2 MB
  short* wvt = (short*)(ws + 8 * MB);     // [2048][512]      2 MB
  short* wzt = (short*)(ws + 10 * MB);    // [512][2048]      2 MB
  short* Qb  = (short*)(ws + 12 * MB);    // frag-linear Q   16 MB
  short* Kb  = (short*)(ws + 28 * MB);    // frag-linear K   16 MB
  short* Vt  = (short*)(ws + 44 * MB);    // frag-linear V   16 MB
  short* att = (short*)(ws + 60 * MB);    // [4096][2048]    16 MB

  k_cvt<<<2048, 256, 0, stream>>>(x, xb, (BATCH * NSEQ * DIN) / 4);
  k_transpose<<<dim3(32, 8), 256, 0, stream>>>(Wq, wqt, DIN, INNER);
  k_transpose<<<dim3(32, 8), 256, 0, stream>>>(Wk, wkt, DIN, INNER);
  k_transpose<<<dim3(32, 8), 256, 0, stream>>>(Wv, wvt, DIN, INNER);
  k_transpose<<<dim3(8, 32), 256, 0, stream>>>(Wz, wzt, INNER, DIN);

  dim3 gQKV(32, 32);  // M/128, N/64
  k_gemm<1><<<gQKV, 256, 0, stream>>>(xb, wqt, Qb, nullptr, 4096, INNER, DIN);
  k_gemm<0><<<gQKV, 256, 0, stream>>>(xb, wkt, Kb, nullptr, 4096, INNER, DIN);
  k_gemm<2><<<gQKV, 256, 0, stream>>>(xb, wvt, Vt, nullptr, 4096, INNER, DIN);

  k_attn<<<dim3(NSEQ / 64, HEADS, BATCH), 128, 0, stream>>>(Qb, Kb, Vt, att);

  k_gemm<3><<<dim3(32, 8), 256, 0, stream>>>(att, wzt, d_out, bz, 4096, DIN, INNER);
}

// Round 5
// 315.018 us; speedup vs baseline: 2.1165x; 1.0744x over previous
//
#include <hip/hip_runtime.h>

#define HEADS 32
#define DK    64
#define NSEQ  2048
#define BATCH 2
#define DIN   512
#define INNER 2048  // HEADS*DK

typedef float f32x2 __attribute__((ext_vector_type(2)));
typedef float f32x4 __attribute__((ext_vector_type(4)));
typedef float f32x16 __attribute__((ext_vector_type(16)));
typedef short s16x8 __attribute__((ext_vector_type(8)));
typedef short s16x4 __attribute__((ext_vector_type(4)));
typedef unsigned u32x2 __attribute__((ext_vector_type(2)));
typedef unsigned u32x4 __attribute__((ext_vector_type(4)));

__device__ __forceinline__ short f2b(float f) {
  unsigned u = __float_as_uint(f);
  u += 0x7fffu + ((u >> 16) & 1u);   // round-to-nearest-even
  return (short)(u >> 16);
}

__device__ __forceinline__ unsigned cvt_pk_bf16(float lo, float hi) {
  unsigned r;
  asm("v_cvt_pk_bf16_f32 %0, %1, %2" : "=v"(r) : "v"(lo), "v"(hi));
  return r;
}

// cross-half (lane ^ 32) max / add via permlane32_swap (full-rate VALU, no LDS)
__device__ __forceinline__ float xhalf_max(float v) {
  u32x2 r = __builtin_amdgcn_permlane32_swap(__float_as_uint(v), __float_as_uint(v),
                                             false, false);
  return fmaxf(__uint_as_float(r[0]), __uint_as_float(r[1]));
}
__device__ __forceinline__ float xhalf_add(float v) {
  u32x2 r = __builtin_amdgcn_permlane32_swap(__float_as_uint(v), __float_as_uint(v),
                                             false, false);
  return __uint_as_float(r[0]) + __uint_as_float(r[1]);
}

// ---------------- convert x: f32 -> bf16, vectorized ----------------
__global__ __launch_bounds__(256) void k_cvt(const float* __restrict__ in,
                                             short* __restrict__ out, int n4) {
  int i = blockIdx.x * 256 + threadIdx.x;
  if (i < n4) {
    float4 v = reinterpret_cast<const float4*>(in)[i];
    s16x4 o;
    o[0] = f2b(v.x); o[1] = f2b(v.y); o[2] = f2b(v.z); o[3] = f2b(v.w);
    reinterpret_cast<s16x4*>(out)[i] = o;
  }
}

// ------------- transpose W [R][C] f32 -> out [C][R] bf16 -------------
__global__ __launch_bounds__(256) void k_transpose(const float* __restrict__ in,
                                                   short* __restrict__ out,
                                                   int R, int C) {
  __shared__ float tile[64][65];
  const int tc = blockIdx.x * 64;
  const int tr = blockIdx.y * 64;
  const int tx = threadIdx.x & 63;
  const int ty = threadIdx.x >> 6;
#pragma unroll
  for (int rr = ty; rr < 64; rr += 4)
    tile[rr][tx] = in[(size_t)(tr + rr) * C + tc + tx];
  __syncthreads();
#pragma unroll
  for (int rr = ty; rr < 64; rr += 4)
    out[(size_t)(tc + rr) * R + tr + tx] = f2b(tile[tx][rr]);
}

// Fragment-linear layouts per (b,h), elements (n in [0,2048), dk in [0,64)):
//  Q/K (B-operand of 32x32x16):
//    lin = ((n>>5)*4 + (dk>>4))*512 + ((dk>>3)&1)*256 + (n&31)*8 + (dk&7)
//  V (A-operand of PV):
//    lin = (n>>5)*2048 + ((n>>4)&1)*1024 + (dk>>5)*512 + ((n>>3)&1)*256 + (dk&31)*8 + (n&7)

// ---------------- GEMM: A[M][K] bf16 (k-fast) x BT[N][K] bf16 ----------------
// MODE 0: out bf16 frag-linear Q/K layout       (K projection)
// MODE 1: MODE 0 * 0.125*log2e                  (Q projection, exp2-domain scale)
// MODE 2: out bf16 frag-linear V layout         (V projection)
// MODE 3: out f32 [M][N] + bias                 (final projection)
template <int MODE>
__global__ __launch_bounds__(256) void k_gemm(const short* __restrict__ A,
                                              const short* __restrict__ BT,
                                              void* __restrict__ outp,
                                              const float* __restrict__ bias,
                                              int M, int N, int Kd) {
  const int bm = blockIdx.x * 128;
  const int bn = blockIdx.y * 64;
  const int wave = threadIdx.x >> 6, lane = threadIdx.x & 63;
  const int l16 = lane & 15, g = lane >> 4;
  const int m0 = bm + wave * 32;

  const f32x4 ZERO = {0.f, 0.f, 0.f, 0.f};
  f32x4 acc[2][4];
#pragma unroll
  for (int i = 0; i < 2; i++)
#pragma unroll
    for (int c = 0; c < 4; c++) acc[i][c] = ZERO;

  const short* arow0 = A + (size_t)(m0 + l16) * Kd + 8 * g;
  const short* arow1 = arow0 + (size_t)16 * Kd;

  for (int k0 = 0; k0 < Kd; k0 += 32) {
    s16x8 a0 = *reinterpret_cast<const s16x8*>(arow0 + k0);
    s16x8 a1 = *reinterpret_cast<const s16x8*>(arow1 + k0);
#pragma unroll
    for (int c = 0; c < 4; c++) {
      s16x8 bf = *reinterpret_cast<const s16x8*>(
          BT + (size_t)(bn + c * 16 + l16) * Kd + k0 + 8 * g);
      acc[0][c] = __builtin_amdgcn_mfma_f32_16x16x32_bf16(a0, bf, acc[0][c], 0, 0, 0);
      acc[1][c] = __builtin_amdgcn_mfma_f32_16x16x32_bf16(a1, bf, acc[1][c], 0, 0, 0);
    }
  }

#pragma unroll
  for (int i = 0; i < 2; i++)
#pragma unroll
    for (int c = 0; c < 4; c++)
#pragma unroll
      for (int r = 0; r < 4; r++) {
        int row = m0 + i * 16 + 4 * g + r;
        int col = bn + c * 16 + l16;
        float v = acc[i][c][r];
        if (MODE == 3) {
          float* o = (float*)outp;
          o[(size_t)row * N + col] = v + bias[col];
        } else {
          if (MODE == 1) v *= 0.18033688f;  // 0.125 * log2(e): softmax in exp2 domain
          short* o = (short*)outp;
          int b = row >> 11, n = row & 2047;
          int h = col >> 6, dk = col & 63;
          size_t base = (size_t)(b * HEADS + h) * (NSEQ * DK);
          size_t idx;
          if (MODE == 2)
            idx = base + (size_t)((n >> 5) * 2 + ((n >> 4) & 1)) * 1024 +
                  (dk >> 5) * 512 + ((n >> 3) & 1) * 256 + (dk & 31) * 8 + (n & 7);
          else
            idx = base + (size_t)((n >> 5) * 4 + (dk >> 4)) * 512 +
                  ((dk >> 3) & 1) * 256 + (n & 31) * 8 + (dk & 7);
          o[idx] = f2b(v);
        }
      }
}

// ---------------- flash attention, swapped-QK^T in-register softmax ----------
// Q (pre-scaled by 0.125*log2e), K, V in fragment-linear layouts.
// att out: [B*N][H*64] bf16.  grid = (N/64, H, B), block = 128 (2 indep waves).
__global__ __launch_bounds__(128) void k_attn(const short* __restrict__ Q,
                                              const short* __restrict__ K,
                                              const short* __restrict__ VT,
                                              short* __restrict__ att) {
  const int wave = threadIdx.x >> 6, lane = threadIdx.x & 63;
  const int l32 = lane & 31, hi = lane >> 5;
  const int h = blockIdx.y, b = blockIdx.z;
  const int q0 = blockIdx.x * 64 + wave * 32;
  const size_t hb = ((size_t)b * HEADS + h) * (size_t)NSEQ * DK;
  const short* Qh = Q + hb;
  const short* Kh = K + hb;
  const short* Vh = VT + hb;

  // Q B-frags: fully coalesced, base + lane*16B
  s16x8 qf[4];
  {
    const short* qbase = Qh + (size_t)(q0 >> 5) * 2048 + lane * 8;
#pragma unroll
    for (int c = 0; c < 4; c++) qf[c] = *reinterpret_cast<const s16x8*>(qbase + c * 512);
  }

  f32x16 ot[2] = {};              // O^T accum: d-tiles 0/1, col=q, row=d
  float m = -1e30f, lsum = 0.f;

  constexpr int NT = NSEQ / 32;
  s16x8 kfA[4], kfB[4];
  {
    const short* kbase = Kh + lane * 8;
#pragma unroll
    for (int c = 0; c < 4; c++) kfA[c] = *reinterpret_cast<const s16x8*>(kbase + c * 512);
  }

  auto tile = [&](s16x8(&kc)[4], s16x8(&kn)[4], int t) {
    // V A-frags (independent -> issue first)
    const short* vbase = Vh + (size_t)t * 2048 + lane * 8;
    s16x8 vf00 = *reinterpret_cast<const s16x8*>(vbase);         // ks0, dt0
    s16x8 vf01 = *reinterpret_cast<const s16x8*>(vbase + 512);   // ks0, dt1
    s16x8 vf10 = *reinterpret_cast<const s16x8*>(vbase + 1024);  // ks1, dt0
    s16x8 vf11 = *reinterpret_cast<const s16x8*>(vbase + 1536);  // ks1, dt1

    // prefetch next K tile (clamped, branchless)
    int tn = (t + 1 < NT) ? t + 1 : t;
    const short* kbase = Kh + (size_t)tn * 2048 + lane * 8;
#pragma unroll
    for (int c = 0; c < 4; c++) kn[c] = *reinterpret_cast<const s16x8*>(kbase + c * 512);

    // S^T = K . Q^T (log2-domain scores)
    f32x16 st = {};
#pragma unroll
    for (int c = 0; c < 4; c++)
      st = __builtin_amdgcn_mfma_f32_32x32x16_bf16(kc[c], qf[c], st, 0, 0, 0);

    // ---- online softmax, lane-local (v_max3-friendly triples) ----
    float u0 = fmaxf(fmaxf(st[0], st[1]), st[2]);
    float u1 = fmaxf(fmaxf(st[3], st[4]), st[5]);
    float u2 = fmaxf(fmaxf(st[6], st[7]), st[8]);
    float u3 = fmaxf(fmaxf(st[9], st[10]), st[11]);
    float u4 = fmaxf(fmaxf(st[12], st[13]), st[14]);
    float mx = fmaxf(fmaxf(fmaxf(u0, u1), u2), fmaxf(fmaxf(u3, u4), st[15]));
    mx = xhalf_max(mx);

    if (!__all(mx <= m + 11.5f)) {   // defer-max (T13), log2 units
      float mnew = fmaxf(m, mx);
      float alpha = __builtin_amdgcn_exp2f(m - mnew);
      lsum *= alpha;
#pragma unroll
      for (int r = 0; r < 16; r++) { ot[0][r] *= alpha; ot[1][r] *= alpha; }
      m = mnew;
    }

    float p[16];
#pragma unroll
    for (int r = 0; r < 16; r++) p[r] = __builtin_amdgcn_exp2f(st[r] - m);

    // row sum via packed f32 adds
    f32x2 e0 = (f32x2){p[0], p[1]} + (f32x2){p[2], p[3]};
    f32x2 e1 = (f32x2){p[4], p[5]} + (f32x2){p[6], p[7]};
    f32x2 e2 = (f32x2){p[8], p[9]} + (f32x2){p[10], p[11]};
    f32x2 e3 = (f32x2){p[12], p[13]} + (f32x2){p[14], p[15]};
    e0 += e1; e2 += e3; e0 += e2;
    lsum += xhalf_add(e0[0] + e0[1]);

    // ---- P^T B-frag build: cvt_pk pairs + permlane32_swap ----
    // permlane32_swap(lo, hi) -> r[0] = lane<32 ? lo(own) : hi(lane-32)
    //                            r[1] = lane<32 ? lo(lane+32) : hi(own)
    // B-frag word w needs kv = 8*hi_half + 2w(+1); a0..a3 cover kv{0..3}+4hi,
    // kv{8..11}+4hi -> (a0,a2),(a1,a3) swaps give both halves directly (T12).
    unsigned a0 = cvt_pk_bf16(p[0], p[1]),   a1 = cvt_pk_bf16(p[2], p[3]);
    unsigned a2 = cvt_pk_bf16(p[4], p[5]),   a3 = cvt_pk_bf16(p[6], p[7]);
    unsigned a4 = cvt_pk_bf16(p[8], p[9]),   a5 = cvt_pk_bf16(p[10], p[11]);
    unsigned a6 = cvt_pk_bf16(p[12], p[13]), a7 = cvt_pk_bf16(p[14], p[15]);
    u32x2 w0 = __builtin_amdgcn_permlane32_swap(a0, a2, false, false);
    u32x2 w1 = __builtin_amdgcn_permlane32_swap(a1, a3, false, false);
    u32x2 w2 = __builtin_amdgcn_permlane32_swap(a4, a6, false, false);
    u32x2 w3 = __builtin_amdgcn_permlane32_swap(a5, a7, false, false);
    u32x4 pw0 = {w0[0], w1[0], w0[1], w1[1]};
    u32x4 pw1 = {w2[0], w3[0], w2[1], w3[1]};
    s16x8 pf0 = __builtin_bit_cast(s16x8, pw0);
    s16x8 pf1 = __builtin_bit_cast(s16x8, pw1);

    // O^T += V^T . P^T
    ot[0] = __builtin_amdgcn_mfma_f32_32x32x16_bf16(vf00, pf0, ot[0], 0, 0, 0);
    ot[1] = __builtin_amdgcn_mfma_f32_32x32x16_bf16(vf01, pf0, ot[1], 0, 0, 0);
    ot[0] = __builtin_amdgcn_mfma_f32_32x32x16_bf16(vf10, pf1, ot[0], 0, 0, 0);
    ot[1] = __builtin_amdgcn_mfma_f32_32x32x16_bf16(vf11, pf1, ot[1], 0, 0, 0);
  };

  for (int t = 0; t < NT; t += 2) {
    tile(kfA, kfB, t);
    tile(kfB, kfA, t + 1);
  }

  // epilogue: normalize + write att[B*N][H*64]
  float inv = 1.f / lsum;
  size_t arow = ((size_t)b * NSEQ + q0 + l32) * INNER + (size_t)h * DK;
#pragma unroll
  for (int dt = 0; dt < 2; dt++)
#pragma unroll
    for (int gq = 0; gq < 4; gq++) {
      s16x4 w;
#pragma unroll
      for (int j = 0; j < 4; j++) w[j] = f2b(ot[dt][4 * gq + j] * inv);
      *reinterpret_cast<s16x4*>(att + arow + dt * 32 + 8 * gq + 4 * hi) = w;
    }
}

extern "C" void kernel_launch(void* const* d_in, const int* in_sizes, int n_in,
                              void* d_out, int out_size, void* d_ws, size_t ws_size,
                              hipStream_t stream) {
  const float* x  = (const float*)d_in[0];
  const float* Wq = (const float*)d_in[1];
  const float* Wk = (const float*)d_in[2];
  const float* Wv = (const float*)d_in[3];
  const float* Wz = (const float*)d_in[4];
  const float* bz = (const float*)d_in[5];

  char* ws = (char*)d_ws;
  const size_t MB = (size_t)1 << 20;
  short* xb  = (short*)(ws);              // [4096][512]      4 MB
  short* wqt = (short*)(ws + 4 * MB);     // [2048][512]      2 MB
  short* wkt = (short*)(ws + 6 * MB);     // [2048][512]      2 MB
  short* wvt = (short*)(ws + 8 * MB);     // [2048][512]      2 MB
  short* wzt = (short*)(ws + 10 * MB);    // [512][2048]      2 MB
  short* Qb  = (short*)(ws + 12 * MB);    // frag-linear Q   16 MB
  short* Kb  = (short*)(ws + 28 * MB);    // frag-linear K   16 MB
  short* Vt  = (short*)(ws + 44 * MB);    // frag-linear V   16 MB
  short* att = (short*)(ws + 60 * MB);    // [4096][2048]    16 MB

  k_cvt<<<2048, 256, 0, stream>>>(x, xb, (BATCH * NSEQ * DIN) / 4);
  k_transpose<<<dim3(32, 8), 256, 0, stream>>>(Wq, wqt, DIN, INNER);
  k_transpose<<<dim3(32, 8), 256, 0, stream>>>(Wk, wkt, DIN, INNER);
  k_transpose<<<dim3(32, 8), 256, 0, stream>>>(Wv, wvt, DIN, INNER);
  k_transpose<<<dim3(8, 32), 256, 0, stream>>>(Wz, wzt, INNER, DIN);

  dim3 gQKV(32, 32);  // M/128, N/64
  k_gemm<1><<<gQKV, 256, 0, stream>>>(xb, wqt, Qb, nullptr, 4096, INNER, DIN);
  k_gemm<0><<<gQKV, 256, 0, stream>>>(xb, wkt, Kb, nullptr, 4096, INNER, DIN);
  k_gemm<2><<<gQKV, 256, 0, stream>>>(xb, wvt, Vt, nullptr, 4096, INNER, DIN);

  k_attn<<<dim3(NSEQ / 64, HEADS, BATCH), 128, 0, stream>>>(Qb, Kb, Vt, att);

  k_gemm<3><<<dim3(32, 8), 256, 0, stream>>>(att, wzt, d_out, bz, 4096, DIN, INNER);
}

// Round 6
// 225.624 us; speedup vs baseline: 2.9551x; 1.3962x over previous
//
#include <hip/hip_runtime.h>

#define HEADS 32
#define DK    64
#define NSEQ  2048
#define BATCH 2
#define DIN   512
#define INNER 2048  // HEADS*DK

typedef float f32x2 __attribute__((ext_vector_type(2)));
typedef float f32x4 __attribute__((ext_vector_type(4)));
typedef float f32x16 __attribute__((ext_vector_type(16)));
typedef short s16x8 __attribute__((ext_vector_type(8)));
typedef short s16x4 __attribute__((ext_vector_type(4)));
typedef unsigned u32x2 __attribute__((ext_vector_type(2)));
typedef unsigned u32x4 __attribute__((ext_vector_type(4)));

#define AS1 __attribute__((address_space(1)))
#define AS3 __attribute__((address_space(3)))

__device__ __forceinline__ short f2b(float f) {
  unsigned u = __float_as_uint(f);
  u += 0x7fffu + ((u >> 16) & 1u);   // round-to-nearest-even
  return (short)(u >> 16);
}

__device__ __forceinline__ unsigned cvt_pk_bf16(float lo, float hi) {
  unsigned r;
  asm("v_cvt_pk_bf16_f32 %0, %1, %2" : "=v"(r) : "v"(lo), "v"(hi));
  return r;
}

// cross-half (lane ^ 32) max / add via permlane32_swap (full-rate VALU, no LDS)
__device__ __forceinline__ float xhalf_max(float v) {
  u32x2 r = __builtin_amdgcn_permlane32_swap(__float_as_uint(v), __float_as_uint(v),
                                             false, false);
  return fmaxf(__uint_as_float(r[0]), __uint_as_float(r[1]));
}
__device__ __forceinline__ float xhalf_add(float v) {
  u32x2 r = __builtin_amdgcn_permlane32_swap(__float_as_uint(v), __float_as_uint(v),
                                             false, false);
  return __uint_as_float(r[0]) + __uint_as_float(r[1]);
}

// async global->LDS, 16B per lane; lds dest = wave-uniform base + lane*16
__device__ __forceinline__ void gll16(const short* gp, short* lp) {
  __builtin_amdgcn_global_load_lds((const AS1 unsigned*)gp, (AS3 unsigned*)lp, 16, 0, 0);
}

// A-frag-linear (16x16x32 A operand), unit = 16 rows x 32 k = 512 shorts:
//   lin = (m>>4)*(K*16) + (k>>5)*512 + (m&15)*8 + ((k>>3)&3)*128 + (k&7)
// B-frag-linear identical with n in place of m.
// Q/K attn layout per (b,h): lin = (n>>5)*2048 + (dk>>4)*512 + ((dk>>3)&1)*256 + (n&31)*8 + (dk&7)
// V  attn layout per (b,h): lin = (n>>5)*2048 + ((n>>4)&1)*1024 + (dk>>5)*512 + ((n>>3)&1)*256 + (dk&31)*8 + (n&7)

// ---------- convert x: f32 [4096][512] -> bf16 A-frag-linear ----------
__global__ __launch_bounds__(256) void k_cvt(const float* __restrict__ in,
                                             short* __restrict__ out) {
  int t = blockIdx.x * 256 + threadIdx.x;    // 262144 threads, one 16B chunk each
  int m = t >> 6, kc = t & 63;               // kc: 8-elem chunk within row
  const float* src = in + (size_t)m * 512 + kc * 8;
  float4 v0 = *reinterpret_cast<const float4*>(src);
  float4 v1 = *reinterpret_cast<const float4*>(src + 4);
  s16x8 o;
  o[0] = f2b(v0.x); o[1] = f2b(v0.y); o[2] = f2b(v0.z); o[3] = f2b(v0.w);
  o[4] = f2b(v1.x); o[5] = f2b(v1.y); o[6] = f2b(v1.z); o[7] = f2b(v1.w);
  size_t lin = (size_t)(m >> 4) * 8192 + (kc >> 2) * 512 + (kc & 3) * 128 + (m & 15) * 8;
  *reinterpret_cast<s16x8*>(out + lin) = o;
}

// ---- transpose W [R][C] f32 -> out B-frag-linear over (n=C-dim, k=R-dim) ----
__global__ __launch_bounds__(256) void k_transpose(const float* __restrict__ in,
                                                   short* __restrict__ out,
                                                   int R, int C) {
  __shared__ float tile[64][65];
  const int tc = blockIdx.x * 64;
  const int tr = blockIdx.y * 64;
  const int tx = threadIdx.x & 63;
  const int ty = threadIdx.x >> 6;
#pragma unroll
  for (int rr = ty; rr < 64; rr += 4)
    tile[rr][tx] = in[(size_t)(tr + rr) * C + tc + tx];
  __syncthreads();
#pragma unroll
  for (int rr = ty; rr < 64; rr += 4) {
    int n = tc + rr, k = tr + tx;
    size_t lin = (size_t)(n >> 4) * ((size_t)R * 16) + (k >> 5) * 512 +
                 ((k >> 3) & 3) * 128 + (n & 15) * 8 + (k & 7);
    out[lin] = f2b(tile[tx][rr]);
  }
}

// -------- fused QKV projection GEMM: M=4096, N=6144, K=512 --------
// 128x128 block tile, 4 waves of 64x64, BK=32, double-buffered LDS (T3 2-phase).
__global__ __launch_bounds__(256) void k_gemm_qkv(const short* __restrict__ A,
                                                  const short* __restrict__ Bw,
                                                  short* __restrict__ Qb,
                                                  short* __restrict__ Kb,
                                                  short* __restrict__ Vb) {
  __shared__ short sA[2][4096];   // 8 KB per buffer: 8 units of 512
  __shared__ short sB[2][4096];
  const int bm = blockIdx.x * 128;
  const int bn = blockIdx.y * 128;
  const int wave = threadIdx.x >> 6, lane = threadIdx.x & 63;
  const int l16 = lane & 15, g = lane >> 4;
  const int wr = wave >> 1, wc = wave & 1;

  const short* Au = A + ((size_t)(bm >> 4) + wave) * 8192 + lane * 8;   // K=512: unit stride 8192
  const short* Bu = Bw + ((size_t)(bn >> 4) + wave) * 8192 + lane * 8;

  f32x4 acc[4][4] = {};

  auto stage = [&](int buf, int kt) {
    gll16(Au + kt * 512,              &sA[buf][wave * 512]);
    gll16(Au + 4 * 8192 + kt * 512,   &sA[buf][(wave + 4) * 512]);
    gll16(Bu + kt * 512,              &sB[buf][wave * 512]);
    gll16(Bu + 4 * 8192 + kt * 512,   &sB[buf][(wave + 4) * 512]);
  };

  stage(0, 0);
  __syncthreads();                       // implicit vmcnt(0): buf0 ready
  int cur = 0;
  for (int kt = 0; kt < 16; ++kt) {
    if (kt + 1 < 16) stage(cur ^ 1, kt + 1);
    s16x8 a[4], b[4];
#pragma unroll
    for (int i = 0; i < 4; i++)
      a[i] = *reinterpret_cast<const s16x8*>(&sA[cur][(wr * 4 + i) * 512 + lane * 8]);
#pragma unroll
    for (int c = 0; c < 4; c++)
      b[c] = *reinterpret_cast<const s16x8*>(&sB[cur][(wc * 4 + c) * 512 + lane * 8]);
#pragma unroll
    for (int i = 0; i < 4; i++)
#pragma unroll
      for (int c = 0; c < 4; c++)
        acc[i][c] = __builtin_amdgcn_mfma_f32_16x16x32_bf16(a[i], b[c], acc[i][c], 0, 0, 0);
    if (kt + 1 < 16) { __syncthreads(); cur ^= 1; }   // drains vmcnt+lgkm: safe swap
  }

  const int proj = bn >> 11;             // 0=Q 1=K 2=V (block-uniform)
#pragma unroll
  for (int i = 0; i < 4; i++)
#pragma unroll
    for (int c = 0; c < 4; c++)
#pragma unroll
      for (int r = 0; r < 4; r++) {
        int row = bm + wr * 64 + i * 16 + 4 * g + r;      // token
        int col = bn + wc * 64 + c * 16 + l16;
        float v = acc[i][c][r];
        int b = row >> 11, n = row & 2047;
        int nc = col & 2047;
        int h = nc >> 6, dk = nc & 63;
        size_t hb = (size_t)(b * HEADS + h) * (NSEQ * DK);
        if (proj == 2) {
          size_t idx = hb + (size_t)(n >> 5) * 2048 + ((n >> 4) & 1) * 1024 +
                       (dk >> 5) * 512 + ((n >> 3) & 1) * 256 + (dk & 31) * 8 + (n & 7);
          Vb[idx] = f2b(v);
        } else {
          size_t idx = hb + (size_t)(n >> 5) * 2048 + (dk >> 4) * 512 +
                       ((dk >> 3) & 1) * 256 + (n & 31) * 8 + (dk & 7);
          if (proj == 0) Qb[idx] = f2b(v * 0.18033688f);  // 0.125*log2(e)
          else           Kb[idx] = f2b(v);
        }
      }
}

// -------- output projection GEMM: M=4096, N=512, K=2048, f32 out + bias --------
// 64x128 block tile, 2 waves of 64x64, BK=32, double-buffered LDS.
__global__ __launch_bounds__(128) void k_gemm_out(const short* __restrict__ A,
                                                  const short* __restrict__ Bw,
                                                  float* __restrict__ out,
                                                  const float* __restrict__ bias) {
  __shared__ short sA[2][2048];   // 4 KB per buffer: 4 units
  __shared__ short sB[2][4096];   // 8 KB per buffer: 8 units
  const int bm = blockIdx.x * 64;
  const int bn = blockIdx.y * 128;
  const int wave = threadIdx.x >> 6, lane = threadIdx.x & 63;
  const int l16 = lane & 15, g = lane >> 4;

  const short* Au = A + ((size_t)(bm >> 4)) * 32768 + lane * 8;   // K=2048: unit stride 32768
  const short* Bu = Bw + ((size_t)(bn >> 4)) * 32768 + lane * 8;

  f32x4 acc[4][4] = {};

  auto stage = [&](int buf, int kt) {
    gll16(Au + (size_t)(2 * wave + 0) * 32768 + kt * 512, &sA[buf][(2 * wave + 0) * 512]);
    gll16(Au + (size_t)(2 * wave + 1) * 32768 + kt * 512, &sA[buf][(2 * wave + 1) * 512]);
#pragma unroll
    for (int j = 0; j < 4; j++)
      gll16(Bu + (size_t)(4 * wave + j) * 32768 + kt * 512, &sB[buf][(4 * wave + j) * 512]);
  };

  stage(0, 0);
  __syncthreads();
  int cur = 0;
  for (int kt = 0; kt < 64; ++kt) {
    if (kt + 1 < 64) stage(cur ^ 1, kt + 1);
    s16x8 a[4], b[4];
#pragma unroll
    for (int i = 0; i < 4; i++)
      a[i] = *reinterpret_cast<const s16x8*>(&sA[cur][i * 512 + lane * 8]);
#pragma unroll
    for (int c = 0; c < 4; c++)
      b[c] = *reinterpret_cast<const s16x8*>(&sB[cur][(wave * 4 + c) * 512 + lane * 8]);
#pragma unroll
    for (int i = 0; i < 4; i++)
#pragma unroll
      for (int c = 0; c < 4; c++)
        acc[i][c] = __builtin_amdgcn_mfma_f32_16x16x32_bf16(a[i], b[c], acc[i][c], 0, 0, 0);
    if (kt + 1 < 64) { __syncthreads(); cur ^= 1; }
  }

#pragma unroll
  for (int i = 0; i < 4; i++)
#pragma unroll
    for (int c = 0; c < 4; c++)
#pragma unroll
      for (int r = 0; r < 4; r++) {
        int row = bm + i * 16 + 4 * g + r;
        int col = bn + wave * 64 + c * 16 + l16;
        out[(size_t)row * 512 + col] = acc[i][c][r] + bias[col];
      }
}

// ---------------- flash attention, swapped-QK^T in-register softmax ----------
// Q (pre-scaled by 0.125*log2e), K, V in attn fragment-linear layouts.
// att out: A-frag-linear over (mrow = b*2048+q, hd = h*64+dk), unit stride 32768.
__global__ __launch_bounds__(128) void k_attn(const short* __restrict__ Q,
                                              const short* __restrict__ K,
                                              const short* __restrict__ VT,
                                              short* __restrict__ att) {
  const int wave = threadIdx.x >> 6, lane = threadIdx.x & 63;
  const int l32 = lane & 31, hi = lane >> 5;
  const int h = blockIdx.y, b = blockIdx.z;
  const int q0 = blockIdx.x * 64 + wave * 32;
  const size_t hb = ((size_t)b * HEADS + h) * (size_t)NSEQ * DK;
  const short* Qh = Q + hb;
  const short* Kh = K + hb;
  const short* Vh = VT + hb;

  // Q B-frags: fully coalesced, base + lane*16B
  s16x8 qf[4];
  {
    const short* qbase = Qh + (size_t)(q0 >> 5) * 2048 + lane * 8;
#pragma unroll
    for (int c = 0; c < 4; c++) qf[c] = *reinterpret_cast<const s16x8*>(qbase + c * 512);
  }

  f32x16 ot[2] = {};              // O^T accum: d-tiles 0/1, col=q, row=d
  float m = -1e30f, lsum = 0.f;

  constexpr int NT = NSEQ / 32;
  s16x8 kfA[4], kfB[4];
  {
    const short* kbase = Kh + lane * 8;
#pragma unroll
    for (int c = 0; c < 4; c++) kfA[c] = *reinterpret_cast<const s16x8*>(kbase + c * 512);
  }

  auto tile = [&](s16x8(&kc)[4], s16x8(&kn)[4], int t) {
    // V A-frags (independent -> issue first)
    const short* vbase = Vh + (size_t)t * 2048 + lane * 8;
    s16x8 vf00 = *reinterpret_cast<const s16x8*>(vbase);         // ks0, dt0
    s16x8 vf01 = *reinterpret_cast<const s16x8*>(vbase + 512);   // ks0, dt1
    s16x8 vf10 = *reinterpret_cast<const s16x8*>(vbase + 1024);  // ks1, dt0
    s16x8 vf11 = *reinterpret_cast<const s16x8*>(vbase + 1536);  // ks1, dt1

    // prefetch next K tile (clamped, branchless)
    int tn = (t + 1 < NT) ? t + 1 : t;
    const short* kbase = Kh + (size_t)tn * 2048 + lane * 8;
#pragma unroll
    for (int c = 0; c < 4; c++) kn[c] = *reinterpret_cast<const s16x8*>(kbase + c * 512);

    // S^T = K . Q^T (log2-domain scores)
    f32x16 st = {};
#pragma unroll
    for (int c = 0; c < 4; c++)
      st = __builtin_amdgcn_mfma_f32_32x32x16_bf16(kc[c], qf[c], st, 0, 0, 0);

    // ---- online softmax, lane-local (v_max3-friendly triples) ----
    float u0 = fmaxf(fmaxf(st[0], st[1]), st[2]);
    float u1 = fmaxf(fmaxf(st[3], st[4]), st[5]);
    float u2 = fmaxf(fmaxf(st[6], st[7]), st[8]);
    float u3 = fmaxf(fmaxf(st[9], st[10]), st[11]);
    float u4 = fmaxf(fmaxf(st[12], st[13]), st[14]);
    float mx = fmaxf(fmaxf(fmaxf(u0, u1), u2), fmaxf(fmaxf(u3, u4), st[15]));
    mx = xhalf_max(mx);

    if (!__all(mx <= m + 11.5f)) {   // defer-max (T13), log2 units
      float mnew = fmaxf(m, mx);
      float alpha = __builtin_amdgcn_exp2f(m - mnew);
      lsum *= alpha;
#pragma unroll
      for (int r = 0; r < 16; r++) { ot[0][r] *= alpha; ot[1][r] *= alpha; }
      m = mnew;
    }

    float p[16];
#pragma unroll
    for (int r = 0; r < 16; r++) p[r] = __builtin_amdgcn_exp2f(st[r] - m);

    // row sum via packed f32 adds
    f32x2 e0 = (f32x2){p[0], p[1]} + (f32x2){p[2], p[3]};
    f32x2 e1 = (f32x2){p[4], p[5]} + (f32x2){p[6], p[7]};
    f32x2 e2 = (f32x2){p[8], p[9]} + (f32x2){p[10], p[11]};
    f32x2 e3 = (f32x2){p[12], p[13]} + (f32x2){p[14], p[15]};
    e0 += e1; e2 += e3; e0 += e2;
    lsum += xhalf_add(e0[0] + e0[1]);

    // ---- P^T B-frag build: cvt_pk pairs + permlane32_swap (T12) ----
    unsigned a0 = cvt_pk_bf16(p[0], p[1]),   a1 = cvt_pk_bf16(p[2], p[3]);
    unsigned a2 = cvt_pk_bf16(p[4], p[5]),   a3 = cvt_pk_bf16(p[6], p[7]);
    unsigned a4 = cvt_pk_bf16(p[8], p[9]),   a5 = cvt_pk_bf16(p[10], p[11]);
    unsigned a6 = cvt_pk_bf16(p[12], p[13]), a7 = cvt_pk_bf16(p[14], p[15]);
    u32x2 w0 = __builtin_amdgcn_permlane32_swap(a0, a2, false, false);
    u32x2 w1 = __builtin_amdgcn_permlane32_swap(a1, a3, false, false);
    u32x2 w2 = __builtin_amdgcn_permlane32_swap(a4, a6, false, false);
    u32x2 w3 = __builtin_amdgcn_permlane32_swap(a5, a7, false, false);
    u32x4 pw0 = {w0[0], w1[0], w0[1], w1[1]};
    u32x4 pw1 = {w2[0], w3[0], w2[1], w3[1]};
    s16x8 pf0 = __builtin_bit_cast(s16x8, pw0);
    s16x8 pf1 = __builtin_bit_cast(s16x8, pw1);

    // O^T += V^T . P^T
    ot[0] = __builtin_amdgcn_mfma_f32_32x32x16_bf16(vf00, pf0, ot[0], 0, 0, 0);
    ot[1] = __builtin_amdgcn_mfma_f32_32x32x16_bf16(vf01, pf0, ot[1], 0, 0, 0);
    ot[0] = __builtin_amdgcn_mfma_f32_32x32x16_bf16(vf10, pf1, ot[0], 0, 0, 0);
    ot[1] = __builtin_amdgcn_mfma_f32_32x32x16_bf16(vf11, pf1, ot[1], 0, 0, 0);
  };

  for (int t = 0; t < NT; t += 2) {
    tile(kfA, kfB, t);
    tile(kfB, kfA, t + 1);
  }

  // epilogue: normalize + write att in A-frag-linear (unit stride 32768, K=2048)
  float inv = 1.f / lsum;
  size_t aunit = ((size_t)(b * 128) + (size_t)((q0 + l32) >> 4)) * 32768;
  const int mr = l32 & 15;
#pragma unroll
  for (int dt = 0; dt < 2; dt++)
#pragma unroll
    for (int gq = 0; gq < 4; gq++) {
      s16x4 w;
#pragma unroll
      for (int j = 0; j < 4; j++) w[j] = f2b(ot[dt][4 * gq + j] * inv);
      size_t base = aunit + (size_t)(h * 2 + dt) * 512 + gq * 128 + mr * 8 + 4 * hi;
      *reinterpret_cast<s16x4*>(att + base) = w;
    }
}

extern "C" void kernel_launch(void* const* d_in, const int* in_sizes, int n_in,
                              void* d_out, int out_size, void* d_ws, size_t ws_size,
                              hipStream_t stream) {
  const float* x  = (const float*)d_in[0];
  const float* Wq = (const float*)d_in[1];
  const float* Wk = (const float*)d_in[2];
  const float* Wv = (const float*)d_in[3];
  const float* Wz = (const float*)d_in[4];
  const float* bz = (const float*)d_in[5];

  char* ws = (char*)d_ws;
  const size_t MB = (size_t)1 << 20;
  short* xb   = (short*)(ws);             // A-frag-linear x    4 MB
  short* wqkv = (short*)(ws + 4 * MB);    // B-frag-linear QKV  6 MB
  short* wzt  = (short*)(ws + 10 * MB);   // B-frag-linear Wz   2 MB
  short* Qb   = (short*)(ws + 12 * MB);   // attn Q layout     16 MB
  short* Kb   = (short*)(ws + 28 * MB);   // attn K layout     16 MB
  short* Vt   = (short*)(ws + 44 * MB);   // attn V layout     16 MB
  short* att  = (short*)(ws + 60 * MB);   // A-frag-linear att 16 MB

  k_cvt<<<1024, 256, 0, stream>>>(x, xb);
  k_transpose<<<dim3(32, 8), 256, 0, stream>>>(Wq, wqkv,               DIN, INNER);
  k_transpose<<<dim3(32, 8), 256, 0, stream>>>(Wk, wqkv + 1048576,     DIN, INNER);
  k_transpose<<<dim3(32, 8), 256, 0, stream>>>(Wv, wqkv + 2097152,     DIN, INNER);
  k_transpose<<<dim3(8, 32), 256, 0, stream>>>(Wz, wzt,                INNER, DIN);

  k_gemm_qkv<<<dim3(32, 48), 256, 0, stream>>>(xb, wqkv, Qb, Kb, Vt);

  k_attn<<<dim3(NSEQ / 64, HEADS, BATCH), 128, 0, stream>>>(Qb, Kb, Vt, att);

  k_gemm_out<<<dim3(64, 4), 128, 0, stream>>>(att, wzt, (float*)d_out, bz);
}